// Round 4
// baseline (191.864 us; speedup 1.0000x reference)
//
#include <hip/hip_runtime.h>

// Fused MoE router + combine. B=4,S=4096,DIM=2048,BITS=32,HEXP=4 (f32).
// out[t,d] = x[t,d] * ( sum_e v[t,e]*aggr_w[e]*emb[idx[t,e],d] + aggr_b )
// (v,idx) = top4(softmax(x[t]@A1_w.T + A1_b)), descending, ties->lower idx.
//
// Block = 32 tokens, 512 threads (8 waves), grid 512.
// Router: wave (g = wid&1 -> token half of 16, q = wid>>1 -> dim quarter of 512).
//   Lane: tg = lane>>3 -> tokens {16g+tg, 16g+tg+8}; dpos = lane&7 -> 4 dims.
//   x: global->regs (coalesced, no LDS). W: global_load_lds DMA (16B/lane,
//   linear dest, zero VGPRs) into per-wave [32k][32d] buffer; compute reads
//   are ds_read_b128 with 8 distinct 16B spans = banks 0..31 once each
//   (8-way broadcast, conflict-free). acc[2][32] in regs, k-loop unrolled.
//   Double-buffered; per-wave private -> no barriers; vmcnt(0) guards DMA.
// Reduce: shfl_xor over 8 dpos lanes -> red[4][32][36] in LDS (overlaid on W).
// Softmax/top4: 32 threads, 1 per token. Combine: 16 lanes/token, streaming.

#define NTOK 16384
#define DIMV 2048

typedef const __attribute__((address_space(1))) unsigned int* as1_u32p;
typedef __attribute__((address_space(3))) unsigned int* as3_u32p;

__global__ __launch_bounds__(512, 4) void fused_moe(
    const float* __restrict__ x,
    const float* __restrict__ A1w,
    const float* __restrict__ A1b,
    const float* __restrict__ emb,
    const float* __restrict__ aggw,
    const float* __restrict__ aggb,
    float* __restrict__ out)
{
    // 16384 floats = 64KB: 8 waves * 2 bufs * 1024 floats (W staging).
    // After router barrier, overlaid by red[4][32][36] (4608 f) + gates (256 f).
    __shared__ float smem[16384];

    const int tid  = threadIdx.x;
    const int wid  = tid >> 6;
    const int lane = tid & 63;
    const int g    = wid & 1;          // token half: tokens [16g, 16g+16)
    const int q    = wid >> 1;         // dim quarter: dims [512q, 512q+512)
    const int tg   = lane >> 3;        // 0..7
    const int dpos = lane & 7;         // 0..7 -> 4 dims each
    const int tok0 = blockIdx.x << 5;  // 32 tokens per block

    const int t0 = (g << 4) + tg;      // local tokens
    const int t1 = t0 + 8;
    const size_t xrow0 = (size_t)(tok0 + t0) * DIMV;
    const size_t xrow1 = (size_t)(tok0 + t1) * DIMV;
    const int dbase = (q << 9) + (dpos << 2);      // 512q + 4*dpos

    float* wbuf = smem + (wid << 11);  // per-wave 2048 floats (2 x 1024)

    float acc0[32], acc1[32];
    #pragma unroll
    for (int k = 0; k < 32; ++k) { acc0[k] = 0.f; acc1[k] = 0.f; }

    // W staging map (per global_load_lds instr j): lane i -> LDS float [j*256+4i]
    // = row (8j + i>>3), col 4*(i&7) of the [32][32] chunk. Global src per-lane.
    const int wrow = lane >> 3;          // + 8j
    const int wcol = (lane & 7) << 2;
    const float* wsrc_base = A1w + (size_t)wrow * DIMV + (q << 9) + wcol;

    // prologue: DMA W chunk 0 -> buf 0; prefetch x chunk 0
    {
        float* ldst = wbuf;
        #pragma unroll
        for (int j = 0; j < 4; ++j)
            __builtin_amdgcn_global_load_lds(
                (as1_u32p)(const void*)(wsrc_base + (size_t)(j << 3) * DIMV),
                (as3_u32p)(void*)(ldst + (j << 8)), 16, 0, 0);
    }
    float4 xc0 = *(const float4*)&x[xrow0 + dbase];
    float4 xc1 = *(const float4*)&x[xrow1 + dbase];
    asm volatile("s_waitcnt vmcnt(0)" ::: "memory");

    int cur = 0;
    for (int c = 0; c < 16; ++c) {
        const int cn = (c < 15) ? (c + 1) : 15;   // last iter: harmless reload
        // issue next W chunk DMA -> other buffer
        {
            const float* wsrc = wsrc_base + (cn << 5);
            float* ldst = wbuf + ((cur ^ 1) << 10);
            #pragma unroll
            for (int j = 0; j < 4; ++j)
                __builtin_amdgcn_global_load_lds(
                    (as1_u32p)(const void*)(wsrc + (size_t)(j << 3) * DIMV),
                    (as3_u32p)(void*)(ldst + (j << 8)), 16, 0, 0);
        }
        // prefetch next x
        float4 xn0 = *(const float4*)&x[xrow0 + dbase + (cn << 5)];
        float4 xn1 = *(const float4*)&x[xrow1 + dbase + (cn << 5)];
        // compute current chunk: 32 k x 4 dims x 2 tokens
        const float* wb = wbuf + (cur << 10);
        #pragma unroll
        for (int k = 0; k < 32; ++k) {
            const float4 wv = *(const float4*)&wb[(k << 5) + (dpos << 2)];
            acc0[k] = fmaf(xc0.w, wv.w, fmaf(xc0.z, wv.z,
                      fmaf(xc0.y, wv.y, fmaf(xc0.x, wv.x, acc0[k]))));
            acc1[k] = fmaf(xc1.w, wv.w, fmaf(xc1.z, wv.z,
                      fmaf(xc1.y, wv.y, fmaf(xc1.x, wv.x, acc1[k]))));
        }
        // drain DMA (and x prefetch) before next iter reads buf cur^1
        asm volatile("s_waitcnt vmcnt(0)" ::: "memory");
        xc0 = xn0; xc1 = xn1; cur ^= 1;
    }

    // reduce over 8 dpos lanes (same token): xor masks 1,2,4 = low lane bits
    #pragma unroll
    for (int k = 0; k < 32; ++k) {
        float a = acc0[k], b = acc1[k];
        a += __shfl_xor(a, 1); a += __shfl_xor(a, 2); a += __shfl_xor(a, 4);
        b += __shfl_xor(b, 1); b += __shfl_xor(b, 2); b += __shfl_xor(b, 4);
        acc0[k] = a; acc1[k] = b;
    }

    __syncthreads();   // all waves done with W bufs; smem becomes red[4][32][36]
    if (dpos == 0) {
        float* r0 = smem + q * 1152 + t0 * 36;   // red[q][t0][.]
        float* r1 = smem + q * 1152 + t1 * 36;
        #pragma unroll
        for (int j = 0; j < 8; ++j) {
            *(float4*)&r0[j << 2] = make_float4(acc0[4*j], acc0[4*j+1],
                                                acc0[4*j+2], acc0[4*j+3]);
            *(float4*)&r1[j << 2] = make_float4(acc1[4*j], acc1[4*j+1],
                                                acc1[4*j+2], acc1[4*j+3]);
        }
    }
    __syncthreads();

    // softmax + top4 + gates: one thread per token
    float* gates = smem + 4608;
    if (tid < 32) {
        const int t = tid;
        float l[32];
        #pragma unroll
        for (int k = 0; k < 32; ++k)
            l[k] = (smem[0    + t * 36 + k] + smem[1152 + t * 36 + k])
                 + (smem[2304 + t * 36 + k] + smem[3456 + t * 36 + k])
                 + A1b[k];
        float m = l[0];
        #pragma unroll
        for (int k = 1; k < 32; ++k) m = fmaxf(m, l[k]);
        float s = 0.f;
        #pragma unroll
        for (int k = 0; k < 32; ++k) { l[k] = expf(l[k] - m); s += l[k]; }
        const float inv = 1.0f / s;

        unsigned used = 0u;
        #pragma unroll
        for (int e = 0; e < 4; ++e) {
            float best = -1.f; int bi = 0;
            #pragma unroll
            for (int k = 0; k < 32; ++k) {
                bool ok = !((used >> k) & 1u) && (l[k] > best);
                best = ok ? l[k] : best;
                bi   = ok ? k    : bi;
            }
            used |= (1u << bi);
            gates[t * 8 + e]     = best * inv * aggw[e];   // gate * aggr_w[e]
            gates[t * 8 + 4 + e] = __uint_as_float((unsigned)bi);
        }
    }
    __syncthreads();

    // combine + residual: 16 lanes per token; x re-read is L2/L3-warm
    const int tt  = tid >> 4;          // 0..31
    const int l16 = tid & 15;
    const float4 gv = *(const float4*)&gates[tt * 8];
    const unsigned i0 = __float_as_uint(gates[tt * 8 + 4]);
    const unsigned i1 = __float_as_uint(gates[tt * 8 + 5]);
    const unsigned i2 = __float_as_uint(gates[tt * 8 + 6]);
    const unsigned i3 = __float_as_uint(gates[tt * 8 + 7]);
    const float bb = aggb[0];
    const size_t base = (size_t)(tok0 + tt) * DIMV;

    #pragma unroll 4
    for (int it = 0; it < 32; ++it) {
        const int d = (l16 << 2) + (it << 6);
        const float4 xv = *(const float4*)&x[base + d];
        const float4 e0 = *(const float4*)&emb[(size_t)i0 * DIMV + d];
        const float4 e1 = *(const float4*)&emb[(size_t)i1 * DIMV + d];
        const float4 e2 = *(const float4*)&emb[(size_t)i2 * DIMV + d];
        const float4 e3 = *(const float4*)&emb[(size_t)i3 * DIMV + d];
        float4 a, o;
        a.x = fmaf(gv.x, e0.x, fmaf(gv.y, e1.x, fmaf(gv.z, e2.x, fmaf(gv.w, e3.x, bb))));
        a.y = fmaf(gv.x, e0.y, fmaf(gv.y, e1.y, fmaf(gv.z, e2.y, fmaf(gv.w, e3.y, bb))));
        a.z = fmaf(gv.x, e0.z, fmaf(gv.y, e1.z, fmaf(gv.z, e2.z, fmaf(gv.w, e3.z, bb))));
        a.w = fmaf(gv.x, e0.w, fmaf(gv.y, e1.w, fmaf(gv.z, e2.w, fmaf(gv.w, e3.w, bb))));
        o.x = xv.x * a.x; o.y = xv.y * a.y; o.z = xv.z * a.z; o.w = xv.w * a.w;
        *(float4*)&out[base + d] = o;
    }
}

extern "C" void kernel_launch(void* const* d_in, const int* in_sizes, int n_in,
                              void* d_out, int out_size, void* d_ws, size_t ws_size,
                              hipStream_t stream)
{
    (void)in_sizes; (void)n_in; (void)out_size; (void)d_ws; (void)ws_size;
    const float* x    = (const float*)d_in[0];
    const float* A1w  = (const float*)d_in[1];
    const float* A1b  = (const float*)d_in[2];
    const float* emb  = (const float*)d_in[3];
    const float* aggw = (const float*)d_in[4];
    const float* aggb = (const float*)d_in[5];
    float* out = (float*)d_out;

    fused_moe<<<NTOK / 32, 512, 0, stream>>>(x, A1w, A1b, emb, aggw, aggb, out);
}

// Round 5
// 143.458 us; speedup vs baseline: 1.3374x; 1.3374x over previous
//
#include <hip/hip_runtime.h>

// Two-kernel MoE. B=4,S=4096,DIM=2048,BITS=32,HEXP=4 (f32).
// out[t,d] = x[t,d] * ( sum_e v[t,e]*aggr_w[e]*emb[idx[t,e],d] + aggr_b )
// (v,idx) = top4(softmax(x[t]@A1_w.T + A1_b)), descending, ties->lower idx.
//
// K1 router: grid 256 x 512 thr (8 waves). Block = 64 tokens; wave wid owns
//   d-slice [256*wid, 256*wid+256). Token-per-lane: lane = token, acc[32] =
//   full logit partial for that token. W read via WAVE-UNIFORM scalar loads
//   (L2-hot, SALU port, no LDS). x staged global->LDS with
//   global_load_lds (linear dest) using a ROTATED SOURCE map: within each
//   64B row-quarter, lane (4r+c) fetches dim-slot s=(c+r)&3, so the read
//   addr  base + 256*(t>>4) + 16*(t&15) + 4*((s-t)&3)  is <=4-way on banks.
//   Double-buffered, per-wave private, no main-loop barriers (vmcnt only).
// K2 combine: verbatim from the 98.9us round.

#define NTOK 16384
#define DIMV 2048

typedef const __attribute__((address_space(1))) unsigned int* as1_u32p;
typedef __attribute__((address_space(3))) unsigned int* as3_u32p;

__global__ __launch_bounds__(512, 2) void router_k(
    const float* __restrict__ x,
    const float* __restrict__ A1w,
    const float* __restrict__ A1b,
    const float* __restrict__ aggw,
    float* __restrict__ gates)
{
    // floats: x-stage [0,16384) = 8 waves * 2 bufs * 1024 (4KB buf = [64t][16d]);
    // after barrier overlaid: red[8][64][36] = 18432, gates_lds [18432,18944).
    __shared__ float smem[18944];

    const int tid  = threadIdx.x;
    const int lane = tid & 63;
    const int wid  = __builtin_amdgcn_readfirstlane(tid >> 6);  // force SGPR
    const int tok0 = blockIdx.x << 6;          // 64 tokens/block
    const int dbase = wid << 8;                // wave's 256-dim slice

    float* xw = smem + (wid << 11);            // per-wave 2048 floats (2 bufs)

    // rotated-source staging addresses: instr j covers rows 16j..16j+15.
    // lane i -> row (i>>2), slot s = ((i&3) + (i>>2)) & 3  (col 4s within chunk)
    const int srow = lane >> 2;
    const int sslot = ((lane & 3) + (lane >> 2)) & 3;
    const float* xsrc0 = x + (size_t)(tok0 + srow) * DIMV + dbase + (sslot << 2);

    // read addresses for this lane's token t = lane, slots s=0..3 (floats):
    // base + 256*(t>>4) + 16*(t&15) + 4*((s-t)&3)
    const int rbase = ((lane >> 4) << 8) + ((lane & 15) << 4);
    int roff[4];
    #pragma unroll
    for (int s = 0; s < 4; ++s) roff[s] = rbase + (((s - lane) & 3) << 2);

    float acc[32];
    #pragma unroll
    for (int k = 0; k < 32; ++k) acc[k] = 0.f;

    // prologue: stage chunk 0 -> buf 0
    #pragma unroll
    for (int j = 0; j < 4; ++j)
        __builtin_amdgcn_global_load_lds(
            (as1_u32p)(const void*)(xsrc0 + (size_t)(j << 4) * DIMV),
            (as3_u32p)(void*)(xw + (j << 8)), 16, 0, 0);
    asm volatile("s_waitcnt vmcnt(0)" ::: "memory");

    int buf = 0;
    for (int c = 0; c < 16; ++c) {
        // issue next chunk's staging into the other buffer
        if (c < 15) {
            const float* src = xsrc0 + ((c + 1) << 4);
            float* dst = xw + ((buf ^ 1) << 10);
            #pragma unroll
            for (int j = 0; j < 4; ++j)
                __builtin_amdgcn_global_load_lds(
                    (as1_u32p)(const void*)(src + (size_t)(j << 4) * DIMV),
                    (as3_u32p)(void*)(dst + (j << 8)), 16, 0, 0);
        }
        // read this lane's 16 dims of chunk c
        const float* xb = xw + (buf << 10);
        const float4 x0 = *(const float4*)&xb[roff[0]];
        const float4 x1 = *(const float4*)&xb[roff[1]];
        const float4 x2 = *(const float4*)&xb[roff[2]];
        const float4 x3 = *(const float4*)&xb[roff[3]];
        // W: wave-uniform scalar loads (k, c, dbase all uniform)
        const float* wrow = A1w + dbase + (c << 4);
        #pragma unroll
        for (int k = 0; k < 32; ++k) {
            const float4 w0 = *(const float4*)&wrow[k * DIMV];
            const float4 w1 = *(const float4*)&wrow[k * DIMV + 4];
            const float4 w2 = *(const float4*)&wrow[k * DIMV + 8];
            const float4 w3 = *(const float4*)&wrow[k * DIMV + 12];
            float a = acc[k];
            a = fmaf(x0.x, w0.x, a); a = fmaf(x0.y, w0.y, a);
            a = fmaf(x0.z, w0.z, a); a = fmaf(x0.w, w0.w, a);
            a = fmaf(x1.x, w1.x, a); a = fmaf(x1.y, w1.y, a);
            a = fmaf(x1.z, w1.z, a); a = fmaf(x1.w, w1.w, a);
            a = fmaf(x2.x, w2.x, a); a = fmaf(x2.y, w2.y, a);
            a = fmaf(x2.z, w2.z, a); a = fmaf(x2.w, w2.w, a);
            a = fmaf(x3.x, w3.x, a); a = fmaf(x3.y, w3.y, a);
            a = fmaf(x3.z, w3.z, a); a = fmaf(x3.w, w3.w, a);
            acc[k] = a;
        }
        asm volatile("s_waitcnt vmcnt(0)" ::: "memory");
        buf ^= 1;
    }

    // partial logits -> red[wid][t=lane][k]; b128 rows, stride 36 -> 2-way banks
    __syncthreads();                            // everyone done with x-stage
    float* red = smem;
    {
        float* r = red + wid * 2304 + lane * 36;
        #pragma unroll
        for (int q = 0; q < 8; ++q)
            *(float4*)&r[q << 2] = make_float4(acc[4*q], acc[4*q+1],
                                               acc[4*q+2], acc[4*q+3]);
    }
    __syncthreads();

    // softmax + top4 + gates: one thread per token (64 of 512)
    if (tid < 64) {
        const int t = tid;
        float l[32];
        #pragma unroll
        for (int q = 0; q < 8; ++q) {
            float4 v = make_float4(0.f, 0.f, 0.f, 0.f);
            #pragma unroll
            for (int w = 0; w < 8; ++w) {
                const float4 p = *(const float4*)&red[w * 2304 + t * 36 + (q << 2)];
                v.x += p.x; v.y += p.y; v.z += p.z; v.w += p.w;
            }
            l[4*q]   = v.x + A1b[4*q];
            l[4*q+1] = v.y + A1b[4*q+1];
            l[4*q+2] = v.z + A1b[4*q+2];
            l[4*q+3] = v.w + A1b[4*q+3];
        }
        float m = l[0];
        #pragma unroll
        for (int k = 1; k < 32; ++k) m = fmaxf(m, l[k]);
        float s = 0.f;
        #pragma unroll
        for (int k = 0; k < 32; ++k) { l[k] = expf(l[k] - m); s += l[k]; }
        const float inv = 1.0f / s;

        unsigned used = 0u;
        float gv[4]; unsigned iv[4];
        #pragma unroll
        for (int e = 0; e < 4; ++e) {
            float best = -1.f; int bi = 0;
            #pragma unroll
            for (int k = 0; k < 32; ++k) {
                bool ok = !((used >> k) & 1u) && (l[k] > best);
                best = ok ? l[k] : best;
                bi   = ok ? k    : bi;
            }
            used |= (1u << bi);
            gv[e] = best * inv * aggw[e];      // gate * aggr_w[e]
            iv[e] = (unsigned)bi;
        }
        float* gp = gates + (size_t)(tok0 + t) * 8;
        *(float4*)gp = make_float4(gv[0], gv[1], gv[2], gv[3]);
        *(float4*)(gp + 4) = make_float4(__uint_as_float(iv[0]), __uint_as_float(iv[1]),
                                         __uint_as_float(iv[2]), __uint_as_float(iv[3]));
    }
}

// K2: gather + combine + residual (verbatim from the 98.9us round).
__global__ __launch_bounds__(256) void moe_out_k(
    const float* __restrict__ x,
    const float* __restrict__ emb,
    const float* __restrict__ gates,
    const float* __restrict__ aggb,
    float* __restrict__ out)
{
    const int t   = blockIdx.x;
    const int tid = threadIdx.x;
    const float* gp = gates + (size_t)t * 8;
    const float4 g  = *(const float4*)gp;
    const float4 ibits = *(const float4*)(gp + 4);
    const unsigned i0 = __float_as_uint(ibits.x);
    const unsigned i1 = __float_as_uint(ibits.y);
    const unsigned i2 = __float_as_uint(ibits.z);
    const unsigned i3 = __float_as_uint(ibits.w);
    const float b = aggb[0];
    const size_t base = (size_t)t * DIMV;

    #pragma unroll
    for (int h = 0; h < DIMV; h += 1024) {
        const int d = h + (tid << 2);
        const float4 xv = *(const float4*)&x[base + d];
        const float4 e0 = *(const float4*)&emb[(size_t)i0 * DIMV + d];
        const float4 e1 = *(const float4*)&emb[(size_t)i1 * DIMV + d];
        const float4 e2 = *(const float4*)&emb[(size_t)i2 * DIMV + d];
        const float4 e3 = *(const float4*)&emb[(size_t)i3 * DIMV + d];
        float4 a, o;
        a.x = fmaf(g.x, e0.x, fmaf(g.y, e1.x, fmaf(g.z, e2.x, fmaf(g.w, e3.x, b))));
        a.y = fmaf(g.x, e0.y, fmaf(g.y, e1.y, fmaf(g.z, e2.y, fmaf(g.w, e3.y, b))));
        a.z = fmaf(g.x, e0.z, fmaf(g.y, e1.z, fmaf(g.z, e2.z, fmaf(g.w, e3.z, b))));
        a.w = fmaf(g.x, e0.w, fmaf(g.y, e1.w, fmaf(g.z, e2.w, fmaf(g.w, e3.w, b))));
        o.x = xv.x * a.x; o.y = xv.y * a.y; o.z = xv.z * a.z; o.w = xv.w * a.w;
        *(float4*)&out[base + d] = o;
    }
}

extern "C" void kernel_launch(void* const* d_in, const int* in_sizes, int n_in,
                              void* d_out, int out_size, void* d_ws, size_t ws_size,
                              hipStream_t stream)
{
    (void)in_sizes; (void)n_in; (void)out_size; (void)ws_size;
    const float* x    = (const float*)d_in[0];
    const float* A1w  = (const float*)d_in[1];
    const float* A1b  = (const float*)d_in[2];
    const float* emb  = (const float*)d_in[3];
    const float* aggw = (const float*)d_in[4];
    const float* aggb = (const float*)d_in[5];
    float* out   = (float*)d_out;
    float* gates = (float*)d_ws;               // 16384 * 8 f32 = 512 KB

    router_k<<<NTOK / 64, 512, 0, stream>>>(x, A1w, A1b, aggw, gates);
    moe_out_k<<<NTOK, 256, 0, stream>>>(x, emb, gates, aggb, out);
}

// Round 6
// 103.970 us; speedup vs baseline: 1.8454x; 1.3798x over previous
//
#include <hip/hip_runtime.h>

// Two-kernel MoE. B=4,S=4096,DIM=2048,BITS=32,HEXP=4 (f32).
// out[t,d] = x[t,d] * ( sum_e v[t,e]*aggr_w[e]*emb[idx[t,e],d] + aggr_b )
// (v,idx) = top4(softmax(x[t]@A1_w.T + A1_b)), descending, ties->lower idx.
//
// K1 router: grid 512 x 512 thr (8 waves), block = 32 tokens.
//   Wave wid owns dims [256*wid, 256*wid+256). Lane = (t = lane&31 token,
//   h = lane>>5 dim-half): acc[32] = token t's logit partials over the
//   lane's 128 dims. Per 16-dim chunk:
//     x: global->VGPR, 2 dwordx4/lane (token row chunk = 1 cache line).
//     W: global_load_lds (2 instrs, linear dest [32k][16d]) into per-wave
//        double buffer; compute reads are ds_read_b128 with only 2 distinct
//        addresses per wave (h=0/1) -> broadcast, conflict-free.
//   No main-loop barriers (per-wave-private W bufs); vmcnt(0) guards.
//   Then shfl_xor(32) half-combine -> red[8][32][36] -> softmax/top4
//   (1 thread/token) -> gates to d_ws.
// K2 combine: verbatim from the 98.9us round.

#define NTOK 16384
#define DIMV 2048

typedef const __attribute__((address_space(1))) unsigned int* as1_u32p;
typedef __attribute__((address_space(3))) unsigned int* as3_u32p;

__global__ __launch_bounds__(512, 4) void router_k(
    const float* __restrict__ x,
    const float* __restrict__ A1w,
    const float* __restrict__ A1b,
    const float* __restrict__ aggw,
    float* __restrict__ gates)
{
    // floats: W-stage [0, 8192) = 8 waves * 2 bufs * 512 floats (2KB buf).
    // After the barrier, overlaid by red[8][32][36] = 9216 floats.
    __shared__ float smem[9216];

    const int tid  = threadIdx.x;
    const int lane = tid & 63;
    const int wid  = tid >> 6;
    const int t    = lane & 31;               // token within block
    const int h    = lane >> 5;               // dim half (8 of 16 chunk dims)
    const int tok0 = blockIdx.x << 5;         // 32 tokens/block
    const int dbase = wid << 8;               // wave's 256-dim slice

    float* wstage = smem + (wid << 10);       // 2 bufs x 512 floats

    // x addresses: lane reads token t, chunk dims [h*8, h*8+8)
    const float* xrow = x + (size_t)(tok0 + t) * DIMV + dbase + (h << 3);

    // W staging source map: instr j covers k rows 16j..16j+15.
    // lane i -> k row (i>>2)+16j, col floats (i&3)*4. Dest linear matches.
    const float* wsrc_base = A1w + (size_t)(lane >> 2) * DIMV + dbase
                           + ((lane & 3) << 2);

    float acc[32];
    #pragma unroll
    for (int k = 0; k < 32; ++k) acc[k] = 0.f;

    // prologue: stage W chunk 0 -> buf 0; load x chunk 0 -> regs
    #pragma unroll
    for (int j = 0; j < 2; ++j)
        __builtin_amdgcn_global_load_lds(
            (as1_u32p)(const void*)(wsrc_base + (size_t)(j << 4) * DIMV),
            (as3_u32p)(void*)(wstage + (j << 8)), 16, 0, 0);
    float4 xa = *(const float4*)(xrow);
    float4 xb = *(const float4*)(xrow + 4);
    asm volatile("s_waitcnt vmcnt(0)" ::: "memory");

    int buf = 0;
    for (int c = 0; c < 16; ++c) {
        float4 xna, xnb;
        if (c < 15) {
            // issue next W chunk into the other buffer
            const float* src = wsrc_base + ((c + 1) << 4);
            float* dst = wstage + ((buf ^ 1) << 9);
            #pragma unroll
            for (int j = 0; j < 2; ++j)
                __builtin_amdgcn_global_load_lds(
                    (as1_u32p)(const void*)(src + (size_t)(j << 4) * DIMV),
                    (as3_u32p)(void*)(dst + (j << 8)), 16, 0, 0);
            // prefetch next x chunk
            xna = *(const float4*)(xrow + ((c + 1) << 4));
            xnb = *(const float4*)(xrow + ((c + 1) << 4) + 4);
        }
        // compute chunk c: 32 k x 8 dims; W reads are 2-address broadcasts
        const float* wb = wstage + (buf << 9);
        #pragma unroll
        for (int k = 0; k < 32; ++k) {
            const float4 w0 = *(const float4*)&wb[(k << 4) + (h << 3)];
            const float4 w1 = *(const float4*)&wb[(k << 4) + (h << 3) + 4];
            float a = acc[k];
            a = fmaf(xa.x, w0.x, a); a = fmaf(xa.y, w0.y, a);
            a = fmaf(xa.z, w0.z, a); a = fmaf(xa.w, w0.w, a);
            a = fmaf(xb.x, w1.x, a); a = fmaf(xb.y, w1.y, a);
            a = fmaf(xb.z, w1.z, a); a = fmaf(xb.w, w1.w, a);
            acc[k] = a;
        }
        asm volatile("s_waitcnt vmcnt(0)" ::: "memory");
        xa = xna; xb = xnb; buf ^= 1;
    }

    // combine dim halves: lane t (h=0) accumulates lane t+32's partial
    #pragma unroll
    for (int k = 0; k < 32; ++k) acc[k] += __shfl_xor(acc[k], 32);

    __syncthreads();                           // all waves done with W stage
    float* red = smem;                         // red[8][32][36]
    if (lane < 32) {
        float* r = red + wid * 1152 + t * 36;
        #pragma unroll
        for (int q = 0; q < 8; ++q)
            *(float4*)&r[q << 2] = make_float4(acc[4*q], acc[4*q+1],
                                               acc[4*q+2], acc[4*q+3]);
    }
    __syncthreads();

    // softmax + top4 + gates: one thread per token (32 of 512)
    if (tid < 32) {
        const int tt = tid;
        float l[32];
        #pragma unroll
        for (int q = 0; q < 8; ++q) {
            float4 v = make_float4(0.f, 0.f, 0.f, 0.f);
            #pragma unroll
            for (int w = 0; w < 8; ++w) {
                const float4 p = *(const float4*)&red[w * 1152 + tt * 36 + (q << 2)];
                v.x += p.x; v.y += p.y; v.z += p.z; v.w += p.w;
            }
            l[4*q]   = v.x + A1b[4*q];
            l[4*q+1] = v.y + A1b[4*q+1];
            l[4*q+2] = v.z + A1b[4*q+2];
            l[4*q+3] = v.w + A1b[4*q+3];
        }
        float m = l[0];
        #pragma unroll
        for (int k = 1; k < 32; ++k) m = fmaxf(m, l[k]);
        float s = 0.f;
        #pragma unroll
        for (int k = 0; k < 32; ++k) { l[k] = expf(l[k] - m); s += l[k]; }
        const float inv = 1.0f / s;

        unsigned used = 0u;
        float gv[4]; unsigned iv[4];
        #pragma unroll
        for (int e = 0; e < 4; ++e) {
            float best = -1.f; int bi = 0;
            #pragma unroll
            for (int k = 0; k < 32; ++k) {
                bool ok = !((used >> k) & 1u) && (l[k] > best);
                best = ok ? l[k] : best;
                bi   = ok ? k    : bi;
            }
            used |= (1u << bi);
            gv[e] = best * inv * aggw[e];      // gate * aggr_w[e]
            iv[e] = (unsigned)bi;
        }
        float* gp = gates + (size_t)(tok0 + tt) * 8;
        *(float4*)gp = make_float4(gv[0], gv[1], gv[2], gv[3]);
        *(float4*)(gp + 4) = make_float4(__uint_as_float(iv[0]), __uint_as_float(iv[1]),
                                         __uint_as_float(iv[2]), __uint_as_float(iv[3]));
    }
}

// K2: gather + combine + residual (verbatim from the 98.9us round).
__global__ __launch_bounds__(256) void moe_out_k(
    const float* __restrict__ x,
    const float* __restrict__ emb,
    const float* __restrict__ gates,
    const float* __restrict__ aggb,
    float* __restrict__ out)
{
    const int t   = blockIdx.x;
    const int tid = threadIdx.x;
    const float* gp = gates + (size_t)t * 8;
    const float4 g  = *(const float4*)gp;
    const float4 ibits = *(const float4*)(gp + 4);
    const unsigned i0 = __float_as_uint(ibits.x);
    const unsigned i1 = __float_as_uint(ibits.y);
    const unsigned i2 = __float_as_uint(ibits.z);
    const unsigned i3 = __float_as_uint(ibits.w);
    const float b = aggb[0];
    const size_t base = (size_t)t * DIMV;

    #pragma unroll
    for (int h = 0; h < DIMV; h += 1024) {
        const int d = h + (tid << 2);
        const float4 xv = *(const float4*)&x[base + d];
        const float4 e0 = *(const float4*)&emb[(size_t)i0 * DIMV + d];
        const float4 e1 = *(const float4*)&emb[(size_t)i1 * DIMV + d];
        const float4 e2 = *(const float4*)&emb[(size_t)i2 * DIMV + d];
        const float4 e3 = *(const float4*)&emb[(size_t)i3 * DIMV + d];
        float4 a, o;
        a.x = fmaf(g.x, e0.x, fmaf(g.y, e1.x, fmaf(g.z, e2.x, fmaf(g.w, e3.x, b))));
        a.y = fmaf(g.x, e0.y, fmaf(g.y, e1.y, fmaf(g.z, e2.y, fmaf(g.w, e3.y, b))));
        a.z = fmaf(g.x, e0.z, fmaf(g.y, e1.z, fmaf(g.z, e2.z, fmaf(g.w, e3.z, b))));
        a.w = fmaf(g.x, e0.w, fmaf(g.y, e1.w, fmaf(g.z, e2.w, fmaf(g.w, e3.w, b))));
        o.x = xv.x * a.x; o.y = xv.y * a.y; o.z = xv.z * a.z; o.w = xv.w * a.w;
        *(float4*)&out[base + d] = o;
    }
}

extern "C" void kernel_launch(void* const* d_in, const int* in_sizes, int n_in,
                              void* d_out, int out_size, void* d_ws, size_t ws_size,
                              hipStream_t stream)
{
    (void)in_sizes; (void)n_in; (void)out_size; (void)ws_size;
    const float* x    = (const float*)d_in[0];
    const float* A1w  = (const float*)d_in[1];
    const float* A1b  = (const float*)d_in[2];
    const float* emb  = (const float*)d_in[3];
    const float* aggw = (const float*)d_in[4];
    const float* aggb = (const float*)d_in[5];
    float* out   = (float*)d_out;
    float* gates = (float*)d_ws;               // 16384 * 8 f32 = 512 KB

    router_k<<<NTOK / 32, 512, 0, stream>>>(x, A1w, A1b, aggw, gates);
    moe_out_k<<<NTOK, 256, 0, stream>>>(x, emb, gates, aggb, out);
}